// Round 2
// baseline (8989.899 us; speedup 1.0000x reference)
//
#include <hip/hip_runtime.h>

#define B_DIM 16
#define L_DIM 1024
#define D_DIM 512
#define H_DIM 256
#define K_DIM 4

// ---------------- workspace layout (bytes) ----------------
// [0,64)          : unsigned cnt[16]           (arrive counters, one per batch)
// [256, 33024)    : float hb[2][16][256]       (double-buffered h state)
// [65536, 327680) : float SEL[16384*4]         (softmaxed selections)
// [327680, ...)   : float rN[16384*256]        (reciprocal Lp column norms)
#define OFF_CNT 0
#define OFF_HB  256
#define OFF_SEL 65536
#define OFF_RN  327680

__device__ __forceinline__ float fast_log2(float x) { return __builtin_amdgcn_logf(x); }
__device__ __forceinline__ float fast_exp2(float x) { return __builtin_amdgcn_exp2f(x); }

// ---------------- init: zero counters + h state ----------------
__global__ void k_init(unsigned int* cnt, float* hb) {
    int tid = threadIdx.x;
    if (tid < 16) cnt[tid] = 0u;
    for (int i = tid; i < 2 * 16 * 256; i += 256) hb[i] = 0.0f;
}

// ---------------- selector GEMM + softmax ----------------
// one wave per row; lane l covers d = l*8 .. l*8+7
__global__ __launch_bounds__(256) void k_sel(const float* __restrict__ x,
                                             const float* __restrict__ Wsel,
                                             const float* __restrict__ bsel,
                                             float* __restrict__ SEL) {
    int row  = blockIdx.x * 4 + (threadIdx.x >> 6);
    int lane = threadIdx.x & 63;
    const float4* x4 = (const float4*)(x + (size_t)row * D_DIM);
    const float4* w4 = (const float4*)Wsel;
    float4 xa = x4[lane * 2], xb = x4[lane * 2 + 1];
    float acc[4];
#pragma unroll
    for (int k = 0; k < 4; ++k) {
        float4 wa = w4[k * (D_DIM / 4) + lane * 2];
        float4 wb = w4[k * (D_DIM / 4) + lane * 2 + 1];
        acc[k] = xa.x * wa.x + xa.y * wa.y + xa.z * wa.z + xa.w * wa.w +
                 xb.x * wb.x + xb.y * wb.y + xb.z * wb.z + xb.w * wb.w;
    }
#pragma unroll
    for (int off = 1; off < 64; off <<= 1) {
#pragma unroll
        for (int k = 0; k < 4; ++k) acc[k] += __shfl_xor(acc[k], off, 64);
    }
    if (lane == 0) {
        float z[4], mx = -1e30f;
#pragma unroll
        for (int k = 0; k < 4; ++k) { z[k] = acc[k] + bsel[k]; mx = fmaxf(mx, z[k]); }
        float e[4], s = 0.0f;
#pragma unroll
        for (int k = 0; k < 4; ++k) { e[k] = fast_exp2((z[k] - mx) * 1.4426950408889634f); s += e[k]; }
        float inv = 1.0f / s;
        float4 o = { e[0] * inv, e[1] * inv, e[2] * inv, e[3] * inv };
        ((float4*)SEL)[row] = o;
    }
}

// ---------------- U = X @ W_B^T (f32 tiled GEMM), written into d_out ----------------
#define GBM 64
#define GBN 64
#define GBK 32
__global__ __launch_bounds__(256) void k_u(const float* __restrict__ X,
                                           const float* __restrict__ W,
                                           float* __restrict__ U) {
    __shared__ float Xs[GBK][GBM + 1];
    __shared__ float Ws[GBK][GBN + 1];
    int tid = threadIdx.x;
    int rb = blockIdx.y * GBM;
    int cb = blockIdx.x * GBN;
    int tr = tid >> 4, tc = tid & 15;
    int lrow = tid >> 2;
    int lcol = (tid & 3) * 8;
    float acc[4][4] = {};
    for (int kt = 0; kt < D_DIM; kt += GBK) {
        float4 xa = *(const float4*)(X + (size_t)(rb + lrow) * D_DIM + kt + lcol);
        float4 xb = *(const float4*)(X + (size_t)(rb + lrow) * D_DIM + kt + lcol + 4);
        float4 wa = *(const float4*)(W + (size_t)(cb + lrow) * D_DIM + kt + lcol);
        float4 wb = *(const float4*)(W + (size_t)(cb + lrow) * D_DIM + kt + lcol + 4);
        __syncthreads();
        Xs[lcol + 0][lrow] = xa.x; Xs[lcol + 1][lrow] = xa.y;
        Xs[lcol + 2][lrow] = xa.z; Xs[lcol + 3][lrow] = xa.w;
        Xs[lcol + 4][lrow] = xb.x; Xs[lcol + 5][lrow] = xb.y;
        Xs[lcol + 6][lrow] = xb.z; Xs[lcol + 7][lrow] = xb.w;
        Ws[lcol + 0][lrow] = wa.x; Ws[lcol + 1][lrow] = wa.y;
        Ws[lcol + 2][lrow] = wa.z; Ws[lcol + 3][lrow] = wa.w;
        Ws[lcol + 4][lrow] = wb.x; Ws[lcol + 5][lrow] = wb.y;
        Ws[lcol + 6][lrow] = wb.z; Ws[lcol + 7][lrow] = wb.w;
        __syncthreads();
#pragma unroll
        for (int kk = 0; kk < GBK; ++kk) {
            float a0 = Xs[kk][tr * 4 + 0], a1 = Xs[kk][tr * 4 + 1];
            float a2 = Xs[kk][tr * 4 + 2], a3 = Xs[kk][tr * 4 + 3];
            float b0 = Ws[kk][tc * 4 + 0], b1 = Ws[kk][tc * 4 + 1];
            float b2 = Ws[kk][tc * 4 + 2], b3 = Ws[kk][tc * 4 + 3];
            acc[0][0] = fmaf(a0, b0, acc[0][0]); acc[0][1] = fmaf(a0, b1, acc[0][1]);
            acc[0][2] = fmaf(a0, b2, acc[0][2]); acc[0][3] = fmaf(a0, b3, acc[0][3]);
            acc[1][0] = fmaf(a1, b0, acc[1][0]); acc[1][1] = fmaf(a1, b1, acc[1][1]);
            acc[1][2] = fmaf(a1, b2, acc[1][2]); acc[1][3] = fmaf(a1, b3, acc[1][3]);
            acc[2][0] = fmaf(a2, b0, acc[2][0]); acc[2][1] = fmaf(a2, b1, acc[2][1]);
            acc[2][2] = fmaf(a2, b2, acc[2][2]); acc[2][3] = fmaf(a2, b3, acc[2][3]);
            acc[3][0] = fmaf(a3, b0, acc[3][0]); acc[3][1] = fmaf(a3, b1, acc[3][1]);
            acc[3][2] = fmaf(a3, b2, acc[3][2]); acc[3][3] = fmaf(a3, b3, acc[3][3]);
        }
        __syncthreads();
    }
#pragma unroll
    for (int mi = 0; mi < 4; ++mi) {
        float4 v = { acc[mi][0], acc[mi][1], acc[mi][2], acc[mi][3] };
        *(float4*)(U + (size_t)(rb + tr * 4 + mi) * H_DIM + cb + tc * 4) = v;
    }
}

// ---------------- reciprocal Lp column norms ----------------
// wg handles (b, 16 consecutive t); thread = column j
__global__ __launch_bounds__(256) void k_norm(const float* __restrict__ M,
                                              const float* __restrict__ SEL,
                                              float* __restrict__ rN) {
    int wg = blockIdx.x;
    int b = wg >> 6;
    int t0 = (wg & 63) << 4;
    int j = threadIdx.x;
    float s[16][4];
#pragma unroll
    for (int tt = 0; tt < 16; ++tt) {
        float4 sv = ((const float4*)SEL)[b * L_DIM + t0 + tt];
        s[tt][0] = sv.x; s[tt][1] = sv.y; s[tt][2] = sv.z; s[tt][3] = sv.w;
    }
    float acc[16] = {};
    const float4* M4 = (const float4*)M;
    for (int i = 0; i < H_DIM; ++i) {
        float4 m = M4[i * H_DIM + j];
#pragma unroll
        for (int tt = 0; tt < 16; ++tt) {
            float a = fmaf(m.x, s[tt][0], fmaf(m.y, s[tt][1],
                      fmaf(m.z, s[tt][2], m.w * s[tt][3])));
            a = fabsf(a);
            acc[tt] += fast_exp2(1.2f * fast_log2(a));  // |a|^1.2 ; a==0 -> exp2(-inf)=0
        }
    }
#pragma unroll
    for (int tt = 0; tt < 16; ++tt) {
        // rN = acc^(-1/1.2)
        rN[(size_t)(b * L_DIM + t0 + tt) * H_DIM + j] =
            fast_exp2(-0.8333333333f * fast_log2(acc[tt]));
    }
}

// ---------------- sequential scan ----------------
// 64 wgs: (b = wg&15, slice = wg>>4) so all 4 slices of a batch land on the
// same XCD under round-robin dispatch.
// Each wg: rows ig = slice*64 + (tid&63); wave q owns j in [q*64, q*64+64).
// A_dict slice register-resident: 256 f32/thread.
__global__ __launch_bounds__(256, 1) void k_scan(const float* __restrict__ M,
                                                 const float* __restrict__ SEL,
                                                 const float* __restrict__ rN,
                                                 float* __restrict__ out,
                                                 float* hb, unsigned int* cnt) {
    const int wg = blockIdx.x;
    const int b = wg & 15;
    const int slice = wg >> 4;
    const int tid = threadIdx.x;
    const int q = tid >> 6;
    const int ti = tid & 63;
    const int ig = slice * 64 + ti;

    float m[256];
    {
        const float4* M4 = (const float4*)M;
#pragma unroll
        for (int jj = 0; jj < 64; ++jj) {
            float4 v = M4[ig * H_DIM + q * 64 + jj];
            m[jj * 4 + 0] = v.x; m[jj * 4 + 1] = v.y;
            m[jj * 4 + 2] = v.z; m[jj * 4 + 3] = v.w;
        }
    }

    __shared__ float g_lds[256];
    __shared__ float part_lds[256];
    unsigned int* cb = cnt + b;

#pragma unroll 1
    for (int t = 0; t < L_DIM; ++t) {
        if (t > 0) {
            unsigned int target = (unsigned int)(4 * t);
            while (__hip_atomic_load(cb, __ATOMIC_ACQUIRE, __HIP_MEMORY_SCOPE_AGENT) < target)
                __builtin_amdgcn_s_sleep(1);
        }
        const float* hsrc = hb + (size_t)(t & 1) * (16 * 256) + b * 256;
        float h = __hip_atomic_load(hsrc + tid, __ATOMIC_RELAXED, __HIP_MEMORY_SCOPE_AGENT);
        float g = h * rN[(size_t)(b * L_DIM + t) * H_DIM + tid];
        float uval = 0.0f;
        if (tid < 64) uval = out[(size_t)(b * L_DIM + t) * H_DIM + ig];
        g_lds[tid] = g;
        __syncthreads();

        float4 s4 = ((const float4*)SEL)[b * L_DIM + t];
        float acc0 = 0, acc1 = 0, acc2 = 0, acc3 = 0;
#pragma unroll
        for (int jj = 0; jj < 64; ++jj) {
            float gj = g_lds[q * 64 + jj];
            acc0 = fmaf(m[jj * 4 + 0], gj, acc0);
            acc1 = fmaf(m[jj * 4 + 1], gj, acc1);
            acc2 = fmaf(m[jj * 4 + 2], gj, acc2);
            acc3 = fmaf(m[jj * 4 + 3], gj, acc3);
        }
        float part = fmaf(acc0, s4.x, fmaf(acc1, s4.y, fmaf(acc2, s4.z, acc3 * s4.w)));
        part_lds[q * 64 + ti] = part;
        __syncthreads();

        if (tid < 64) {
            float hn = part_lds[tid] + part_lds[64 + tid] +
                       part_lds[128 + tid] + part_lds[192 + tid] + uval;
            out[(size_t)(b * L_DIM + t) * H_DIM + ig] = hn;
            __hip_atomic_store(hb + (size_t)((t + 1) & 1) * (16 * 256) + b * 256 + ig,
                               hn, __ATOMIC_RELAXED, __HIP_MEMORY_SCOPE_AGENT);
        }
        __syncthreads();
        if (tid == 0)
            __hip_atomic_fetch_add(cb, 1u, __ATOMIC_RELEASE, __HIP_MEMORY_SCOPE_AGENT);
    }
}

extern "C" void kernel_launch(void* const* d_in, const int* in_sizes, int n_in,
                              void* d_out, int out_size, void* d_ws, size_t ws_size,
                              hipStream_t stream) {
    const float* x    = (const float*)d_in[0];  // (16,1024,512)
    const float* Wsel = (const float*)d_in[1];  // (4,512)
    const float* bsel = (const float*)d_in[2];  // (4,)
    const float* W_B  = (const float*)d_in[3];  // (256,512)
    const float* M    = (const float*)d_in[4];  // (256,256,4)
    float* out = (float*)d_out;                 // (16,1024,256)

    char* ws = (char*)d_ws;
    unsigned int* cnt = (unsigned int*)(ws + OFF_CNT);
    float* hb  = (float*)(ws + OFF_HB);
    float* SEL = (float*)(ws + OFF_SEL);
    float* rN  = (float*)(ws + OFF_RN);

    k_init<<<1, 256, 0, stream>>>(cnt, hb);
    k_sel<<<(B_DIM * L_DIM) / 4, 256, 0, stream>>>(x, Wsel, bsel, SEL);
    k_u<<<dim3(H_DIM / GBN, (B_DIM * L_DIM) / GBM), 256, 0, stream>>>(x, W_B, out);
    k_norm<<<(B_DIM * L_DIM) / 16, 256, 0, stream>>>(M, SEL, rN);
    k_scan<<<64, 256, 0, stream>>>(M, SEL, rN, out, hb, cnt);
}

// Round 3
// 5931.507 us; speedup vs baseline: 1.5156x; 1.5156x over previous
//
#include <hip/hip_runtime.h>

#define B_DIM 16
#define L_DIM 1024
#define D_DIM 512
#define H_DIM 256
#define K_DIM 4

#define SLICES 8        // wgs per batch
#define RPW 32          // rows per wg (H_DIM / SLICES)

// ---------------- workspace layout (bytes) ----------------
#define OFF_CNT 0
#define OFF_HB  256
#define OFF_SEL 65536
#define OFF_RN  327680

__device__ __forceinline__ float fast_log2(float x) { return __builtin_amdgcn_logf(x); }
__device__ __forceinline__ float fast_exp2(float x) { return __builtin_amdgcn_exp2f(x); }

// ---------------- init: zero counters + h state ----------------
__global__ void k_init(unsigned int* cnt, float* hb) {
    int tid = threadIdx.x;
    if (tid < 16) cnt[tid] = 0u;
    for (int i = tid; i < 2 * 16 * 256; i += 256) hb[i] = 0.0f;
}

// ---------------- selector GEMM + softmax ----------------
__global__ __launch_bounds__(256) void k_sel(const float* __restrict__ x,
                                             const float* __restrict__ Wsel,
                                             const float* __restrict__ bsel,
                                             float* __restrict__ SEL) {
    int row  = blockIdx.x * 4 + (threadIdx.x >> 6);
    int lane = threadIdx.x & 63;
    const float4* x4 = (const float4*)(x + (size_t)row * D_DIM);
    const float4* w4 = (const float4*)Wsel;
    float4 xa = x4[lane * 2], xb = x4[lane * 2 + 1];
    float acc[4];
#pragma unroll
    for (int k = 0; k < 4; ++k) {
        float4 wa = w4[k * (D_DIM / 4) + lane * 2];
        float4 wb = w4[k * (D_DIM / 4) + lane * 2 + 1];
        acc[k] = xa.x * wa.x + xa.y * wa.y + xa.z * wa.z + xa.w * wa.w +
                 xb.x * wb.x + xb.y * wb.y + xb.z * wb.z + xb.w * wb.w;
    }
#pragma unroll
    for (int off = 1; off < 64; off <<= 1) {
#pragma unroll
        for (int k = 0; k < 4; ++k) acc[k] += __shfl_xor(acc[k], off, 64);
    }
    if (lane == 0) {
        float z[4], mx = -1e30f;
#pragma unroll
        for (int k = 0; k < 4; ++k) { z[k] = acc[k] + bsel[k]; mx = fmaxf(mx, z[k]); }
        float e[4], s = 0.0f;
#pragma unroll
        for (int k = 0; k < 4; ++k) { e[k] = fast_exp2((z[k] - mx) * 1.4426950408889634f); s += e[k]; }
        float inv = 1.0f / s;
        float4 o = { e[0] * inv, e[1] * inv, e[2] * inv, e[3] * inv };
        ((float4*)SEL)[row] = o;
    }
}

// ---------------- U = X @ W_B^T (f32 tiled GEMM), written into d_out ----------------
#define GBM 64
#define GBN 64
#define GBK 32
__global__ __launch_bounds__(256) void k_u(const float* __restrict__ X,
                                           const float* __restrict__ W,
                                           float* __restrict__ U) {
    __shared__ float Xs[GBK][GBM + 1];
    __shared__ float Ws[GBK][GBN + 1];
    int tid = threadIdx.x;
    int rb = blockIdx.y * GBM;
    int cb = blockIdx.x * GBN;
    int tr = tid >> 4, tc = tid & 15;
    int lrow = tid >> 2;
    int lcol = (tid & 3) * 8;
    float acc[4][4] = {};
    for (int kt = 0; kt < D_DIM; kt += GBK) {
        float4 xa = *(const float4*)(X + (size_t)(rb + lrow) * D_DIM + kt + lcol);
        float4 xb = *(const float4*)(X + (size_t)(rb + lrow) * D_DIM + kt + lcol + 4);
        float4 wa = *(const float4*)(W + (size_t)(cb + lrow) * D_DIM + kt + lcol);
        float4 wb = *(const float4*)(W + (size_t)(cb + lrow) * D_DIM + kt + lcol + 4);
        __syncthreads();
        Xs[lcol + 0][lrow] = xa.x; Xs[lcol + 1][lrow] = xa.y;
        Xs[lcol + 2][lrow] = xa.z; Xs[lcol + 3][lrow] = xa.w;
        Xs[lcol + 4][lrow] = xb.x; Xs[lcol + 5][lrow] = xb.y;
        Xs[lcol + 6][lrow] = xb.z; Xs[lcol + 7][lrow] = xb.w;
        Ws[lcol + 0][lrow] = wa.x; Ws[lcol + 1][lrow] = wa.y;
        Ws[lcol + 2][lrow] = wa.z; Ws[lcol + 3][lrow] = wa.w;
        Ws[lcol + 4][lrow] = wb.x; Ws[lcol + 5][lrow] = wb.y;
        Ws[lcol + 6][lrow] = wb.z; Ws[lcol + 7][lrow] = wb.w;
        __syncthreads();
#pragma unroll
        for (int kk = 0; kk < GBK; ++kk) {
            float a0 = Xs[kk][tr * 4 + 0], a1 = Xs[kk][tr * 4 + 1];
            float a2 = Xs[kk][tr * 4 + 2], a3 = Xs[kk][tr * 4 + 3];
            float b0 = Ws[kk][tc * 4 + 0], b1 = Ws[kk][tc * 4 + 1];
            float b2 = Ws[kk][tc * 4 + 2], b3 = Ws[kk][tc * 4 + 3];
            acc[0][0] = fmaf(a0, b0, acc[0][0]); acc[0][1] = fmaf(a0, b1, acc[0][1]);
            acc[0][2] = fmaf(a0, b2, acc[0][2]); acc[0][3] = fmaf(a0, b3, acc[0][3]);
            acc[1][0] = fmaf(a1, b0, acc[1][0]); acc[1][1] = fmaf(a1, b1, acc[1][1]);
            acc[1][2] = fmaf(a1, b2, acc[1][2]); acc[1][3] = fmaf(a1, b3, acc[1][3]);
            acc[2][0] = fmaf(a2, b0, acc[2][0]); acc[2][1] = fmaf(a2, b1, acc[2][1]);
            acc[2][2] = fmaf(a2, b2, acc[2][2]); acc[2][3] = fmaf(a2, b3, acc[2][3]);
            acc[3][0] = fmaf(a3, b0, acc[3][0]); acc[3][1] = fmaf(a3, b1, acc[3][1]);
            acc[3][2] = fmaf(a3, b2, acc[3][2]); acc[3][3] = fmaf(a3, b3, acc[3][3]);
        }
        __syncthreads();
    }
#pragma unroll
    for (int mi = 0; mi < 4; ++mi) {
        float4 v = { acc[mi][0], acc[mi][1], acc[mi][2], acc[mi][3] };
        *(float4*)(U + (size_t)(rb + tr * 4 + mi) * H_DIM + cb + tc * 4) = v;
    }
}

// ---------------- reciprocal Lp column norms ----------------
__global__ __launch_bounds__(256) void k_norm(const float* __restrict__ M,
                                              const float* __restrict__ SEL,
                                              float* __restrict__ rN) {
    int wg = blockIdx.x;
    int b = wg >> 6;
    int t0 = (wg & 63) << 4;
    int j = threadIdx.x;
    float s[16][4];
#pragma unroll
    for (int tt = 0; tt < 16; ++tt) {
        float4 sv = ((const float4*)SEL)[b * L_DIM + t0 + tt];
        s[tt][0] = sv.x; s[tt][1] = sv.y; s[tt][2] = sv.z; s[tt][3] = sv.w;
    }
    float acc[16] = {};
    const float4* M4 = (const float4*)M;
    for (int i = 0; i < H_DIM; ++i) {
        float4 m = M4[i * H_DIM + j];
#pragma unroll
        for (int tt = 0; tt < 16; ++tt) {
            float a = fmaf(m.x, s[tt][0], fmaf(m.y, s[tt][1],
                      fmaf(m.z, s[tt][2], m.w * s[tt][3])));
            a = fabsf(a);
            acc[tt] += fast_exp2(1.2f * fast_log2(a));  // |a|^1.2
        }
    }
#pragma unroll
    for (int tt = 0; tt < 16; ++tt) {
        rN[(size_t)(b * L_DIM + t0 + tt) * H_DIM + j] =
            fast_exp2(-0.8333333333f * fast_log2(acc[tt]));
    }
}

// ---------------- sequential scan ----------------
// 128 wgs: b = wg&15, slice = wg>>4 (8 slices/batch; all slices of a batch
// land on XCD b%8 under round-robin dispatch -> same-L2 communication).
// Each wg owns rows [slice*32, slice*32+32). Thread: wave q owns j-quarter
// [q*64, q*64+64); lane = (row r = ti&31, j-half js = ti>>5).
// Per-thread M slice: 32 j x 4 k = 128 f32, register-resident (~180 VGPR).
__global__ __launch_bounds__(256, 1) void k_scan(const float* __restrict__ M,
                                                 const float* __restrict__ SEL,
                                                 const float* __restrict__ rN,
                                                 float* __restrict__ out,
                                                 float* hb, unsigned int* cnt) {
    const int wg = blockIdx.x;
    const int b = wg & 15;
    const int slice = wg >> 4;
    const int tid = threadIdx.x;
    const int q = tid >> 6;
    const int ti = tid & 63;
    const int r = ti & 31;
    const int js = ti >> 5;
    const int ig = slice * RPW + r;
    const int jbase = q * 64 + js * 32;

    float m[128];
    {
        const float4* M4 = (const float4*)M;
#pragma unroll
        for (int jj = 0; jj < 32; ++jj) {
            float4 v = M4[ig * H_DIM + jbase + jj];
            m[jj * 4 + 0] = v.x; m[jj * 4 + 1] = v.y;
            m[jj * 4 + 2] = v.z; m[jj * 4 + 3] = v.w;
        }
    }

    __shared__ float g_lds[256];
    __shared__ float part_lds[256];
    unsigned int* cb = cnt + b;

#pragma unroll 1
    for (int t = 0; t < L_DIM; ++t) {
        // loads independent of other wgs: issue before the poll
        float rn = rN[(size_t)(b * L_DIM + t) * H_DIM + tid];
        float4 s4 = ((const float4*)SEL)[b * L_DIM + t];
        float uval = 0.0f;
        if (tid < RPW) uval = out[(size_t)(b * L_DIM + t) * H_DIM + slice * RPW + tid];

        if (t > 0) {
            if (tid < 64) {  // only wave 0 polls
                unsigned int target = (unsigned int)(SLICES * t);
                while (__hip_atomic_load(cb, __ATOMIC_RELAXED, __HIP_MEMORY_SCOPE_AGENT) < target)
                    __builtin_amdgcn_s_sleep(2);
                __hip_atomic_load(cb, __ATOMIC_ACQUIRE, __HIP_MEMORY_SCOPE_AGENT);
            }
            __syncthreads();
        }
        float h = __hip_atomic_load(hb + (size_t)(t & 1) * (16 * 256) + b * 256 + tid,
                                    __ATOMIC_RELAXED, __HIP_MEMORY_SCOPE_AGENT);
        g_lds[tid] = h * rn;
        __syncthreads();

        float acc0 = 0, acc1 = 0, acc2 = 0, acc3 = 0;
        const float4* g4 = (const float4*)(g_lds + jbase);
#pragma unroll
        for (int jj4 = 0; jj4 < 8; ++jj4) {
            float4 gv = g4[jj4];
            acc0 = fmaf(m[(jj4 * 4 + 0) * 4 + 0], gv.x, acc0);
            acc1 = fmaf(m[(jj4 * 4 + 0) * 4 + 1], gv.x, acc1);
            acc2 = fmaf(m[(jj4 * 4 + 0) * 4 + 2], gv.x, acc2);
            acc3 = fmaf(m[(jj4 * 4 + 0) * 4 + 3], gv.x, acc3);
            acc0 = fmaf(m[(jj4 * 4 + 1) * 4 + 0], gv.y, acc0);
            acc1 = fmaf(m[(jj4 * 4 + 1) * 4 + 1], gv.y, acc1);
            acc2 = fmaf(m[(jj4 * 4 + 1) * 4 + 2], gv.y, acc2);
            acc3 = fmaf(m[(jj4 * 4 + 1) * 4 + 3], gv.y, acc3);
            acc0 = fmaf(m[(jj4 * 4 + 2) * 4 + 0], gv.z, acc0);
            acc1 = fmaf(m[(jj4 * 4 + 2) * 4 + 1], gv.z, acc1);
            acc2 = fmaf(m[(jj4 * 4 + 2) * 4 + 2], gv.z, acc2);
            acc3 = fmaf(m[(jj4 * 4 + 2) * 4 + 3], gv.z, acc3);
            acc0 = fmaf(m[(jj4 * 4 + 3) * 4 + 0], gv.w, acc0);
            acc1 = fmaf(m[(jj4 * 4 + 3) * 4 + 1], gv.w, acc1);
            acc2 = fmaf(m[(jj4 * 4 + 3) * 4 + 2], gv.w, acc2);
            acc3 = fmaf(m[(jj4 * 4 + 3) * 4 + 3], gv.w, acc3);
        }
        float part = fmaf(acc0, s4.x, fmaf(acc1, s4.y, fmaf(acc2, s4.z, acc3 * s4.w)));
        part_lds[tid] = part;
        __syncthreads();

        if (tid < RPW) {
            float hn = uval;
#pragma unroll
            for (int p = 0; p < 8; ++p) hn += part_lds[tid + 32 * p];
            out[(size_t)(b * L_DIM + t) * H_DIM + slice * RPW + tid] = hn;
            __hip_atomic_store(hb + (size_t)((t + 1) & 1) * (16 * 256) + b * 256 + slice * RPW + tid,
                               hn, __ATOMIC_RELAXED, __HIP_MEMORY_SCOPE_AGENT);
        }
        __syncthreads();
        if (tid == 0)
            __hip_atomic_fetch_add(cb, 1u, __ATOMIC_RELEASE, __HIP_MEMORY_SCOPE_AGENT);
    }
}

extern "C" void kernel_launch(void* const* d_in, const int* in_sizes, int n_in,
                              void* d_out, int out_size, void* d_ws, size_t ws_size,
                              hipStream_t stream) {
    const float* x    = (const float*)d_in[0];  // (16,1024,512)
    const float* Wsel = (const float*)d_in[1];  // (4,512)
    const float* bsel = (const float*)d_in[2];  // (4,)
    const float* W_B  = (const float*)d_in[3];  // (256,512)
    const float* M    = (const float*)d_in[4];  // (256,256,4)
    float* out = (float*)d_out;                 // (16,1024,256)

    char* ws = (char*)d_ws;
    unsigned int* cnt = (unsigned int*)(ws + OFF_CNT);
    float* hb  = (float*)(ws + OFF_HB);
    float* SEL = (float*)(ws + OFF_SEL);
    float* rN  = (float*)(ws + OFF_RN);

    k_init<<<1, 256, 0, stream>>>(cnt, hb);
    k_sel<<<(B_DIM * L_DIM) / 4, 256, 0, stream>>>(x, Wsel, bsel, SEL);
    k_u<<<dim3(H_DIM / GBN, (B_DIM * L_DIM) / GBM), 256, 0, stream>>>(x, W_B, out);
    k_norm<<<(B_DIM * L_DIM) / 16, 256, 0, stream>>>(M, SEL, rN);
    k_scan<<<B_DIM * SLICES, 256, 0, stream>>>(M, SEL, rN, out, hb, cnt);
}

// Round 4
// 3619.350 us; speedup vs baseline: 2.4838x; 1.6388x over previous
//
#include <hip/hip_runtime.h>

#define B_DIM 16
#define L_DIM 1024
#define D_DIM 512
#define H_DIM 256
#define K_DIM 4

#define SLICES 8        // wgs per batch
#define RPW 32          // rows per wg (H_DIM / SLICES)
#define CNT_STRIDE 32   // uints between per-batch counters (128B line each)

// ---------------- workspace layout (bytes) ----------------
#define OFF_CNT 0                      // unsigned cnt[16*32] (padded, 2KB)
#define OFF_HB  4096                   // float hb[2][16][256]
#define OFF_SEL 65536                  // float SEL[16384*4]
#define OFF_RN  327680                 // float rN[16384*256]

__device__ __forceinline__ float fast_log2(float x) { return __builtin_amdgcn_logf(x); }
__device__ __forceinline__ float fast_exp2(float x) { return __builtin_amdgcn_exp2f(x); }

// ---------------- init: zero counters + h state ----------------
__global__ void k_init(unsigned int* cnt, float* hb) {
    int tid = threadIdx.x;
    if (tid < 16 * CNT_STRIDE) cnt[tid] = 0u;
    for (int i = tid; i < 2 * 16 * 256; i += 256) hb[i] = 0.0f;
}

// ---------------- selector GEMM + softmax ----------------
__global__ __launch_bounds__(256) void k_sel(const float* __restrict__ x,
                                             const float* __restrict__ Wsel,
                                             const float* __restrict__ bsel,
                                             float* __restrict__ SEL) {
    int row  = blockIdx.x * 4 + (threadIdx.x >> 6);
    int lane = threadIdx.x & 63;
    const float4* x4 = (const float4*)(x + (size_t)row * D_DIM);
    const float4* w4 = (const float4*)Wsel;
    float4 xa = x4[lane * 2], xb = x4[lane * 2 + 1];
    float acc[4];
#pragma unroll
    for (int k = 0; k < 4; ++k) {
        float4 wa = w4[k * (D_DIM / 4) + lane * 2];
        float4 wb = w4[k * (D_DIM / 4) + lane * 2 + 1];
        acc[k] = xa.x * wa.x + xa.y * wa.y + xa.z * wa.z + xa.w * wa.w +
                 xb.x * wb.x + xb.y * wb.y + xb.z * wb.z + xb.w * wb.w;
    }
#pragma unroll
    for (int off = 1; off < 64; off <<= 1) {
#pragma unroll
        for (int k = 0; k < 4; ++k) acc[k] += __shfl_xor(acc[k], off, 64);
    }
    if (lane == 0) {
        float z[4], mx = -1e30f;
#pragma unroll
        for (int k = 0; k < 4; ++k) { z[k] = acc[k] + bsel[k]; mx = fmaxf(mx, z[k]); }
        float e[4], s = 0.0f;
#pragma unroll
        for (int k = 0; k < 4; ++k) { e[k] = fast_exp2((z[k] - mx) * 1.4426950408889634f); s += e[k]; }
        float inv = 1.0f / s;
        float4 o = { e[0] * inv, e[1] * inv, e[2] * inv, e[3] * inv };
        ((float4*)SEL)[row] = o;
    }
}

// ---------------- U = X @ W_B^T (f32 tiled GEMM), written into d_out ----------------
#define GBM 64
#define GBN 64
#define GBK 32
__global__ __launch_bounds__(256) void k_u(const float* __restrict__ X,
                                           const float* __restrict__ W,
                                           float* __restrict__ U) {
    __shared__ float Xs[GBK][GBM + 1];
    __shared__ float Ws[GBK][GBN + 1];
    int tid = threadIdx.x;
    int rb = blockIdx.y * GBM;
    int cb = blockIdx.x * GBN;
    int tr = tid >> 4, tc = tid & 15;
    int lrow = tid >> 2;
    int lcol = (tid & 3) * 8;
    float acc[4][4] = {};
    for (int kt = 0; kt < D_DIM; kt += GBK) {
        float4 xa = *(const float4*)(X + (size_t)(rb + lrow) * D_DIM + kt + lcol);
        float4 xb = *(const float4*)(X + (size_t)(rb + lrow) * D_DIM + kt + lcol + 4);
        float4 wa = *(const float4*)(W + (size_t)(cb + lrow) * D_DIM + kt + lcol);
        float4 wb = *(const float4*)(W + (size_t)(cb + lrow) * D_DIM + kt + lcol + 4);
        __syncthreads();
        Xs[lcol + 0][lrow] = xa.x; Xs[lcol + 1][lrow] = xa.y;
        Xs[lcol + 2][lrow] = xa.z; Xs[lcol + 3][lrow] = xa.w;
        Xs[lcol + 4][lrow] = xb.x; Xs[lcol + 5][lrow] = xb.y;
        Xs[lcol + 6][lrow] = xb.z; Xs[lcol + 7][lrow] = xb.w;
        Ws[lcol + 0][lrow] = wa.x; Ws[lcol + 1][lrow] = wa.y;
        Ws[lcol + 2][lrow] = wa.z; Ws[lcol + 3][lrow] = wa.w;
        Ws[lcol + 4][lrow] = wb.x; Ws[lcol + 5][lrow] = wb.y;
        Ws[lcol + 6][lrow] = wb.z; Ws[lcol + 7][lrow] = wb.w;
        __syncthreads();
#pragma unroll
        for (int kk = 0; kk < GBK; ++kk) {
            float a0 = Xs[kk][tr * 4 + 0], a1 = Xs[kk][tr * 4 + 1];
            float a2 = Xs[kk][tr * 4 + 2], a3 = Xs[kk][tr * 4 + 3];
            float b0 = Ws[kk][tc * 4 + 0], b1 = Ws[kk][tc * 4 + 1];
            float b2 = Ws[kk][tc * 4 + 2], b3 = Ws[kk][tc * 4 + 3];
            acc[0][0] = fmaf(a0, b0, acc[0][0]); acc[0][1] = fmaf(a0, b1, acc[0][1]);
            acc[0][2] = fmaf(a0, b2, acc[0][2]); acc[0][3] = fmaf(a0, b3, acc[0][3]);
            acc[1][0] = fmaf(a1, b0, acc[1][0]); acc[1][1] = fmaf(a1, b1, acc[1][1]);
            acc[1][2] = fmaf(a1, b2, acc[1][2]); acc[1][3] = fmaf(a1, b3, acc[1][3]);
            acc[2][0] = fmaf(a2, b0, acc[2][0]); acc[2][1] = fmaf(a2, b1, acc[2][1]);
            acc[2][2] = fmaf(a2, b2, acc[2][2]); acc[2][3] = fmaf(a2, b3, acc[2][3]);
            acc[3][0] = fmaf(a3, b0, acc[3][0]); acc[3][1] = fmaf(a3, b1, acc[3][1]);
            acc[3][2] = fmaf(a3, b2, acc[3][2]); acc[3][3] = fmaf(a3, b3, acc[3][3]);
        }
        __syncthreads();
    }
#pragma unroll
    for (int mi = 0; mi < 4; ++mi) {
        float4 v = { acc[mi][0], acc[mi][1], acc[mi][2], acc[mi][3] };
        *(float4*)(U + (size_t)(rb + tr * 4 + mi) * H_DIM + cb + tc * 4) = v;
    }
}

// ---------------- reciprocal Lp column norms ----------------
__global__ __launch_bounds__(256) void k_norm(const float* __restrict__ M,
                                              const float* __restrict__ SEL,
                                              float* __restrict__ rN) {
    int wg = blockIdx.x;
    int b = wg >> 6;
    int t0 = (wg & 63) << 4;
    int j = threadIdx.x;
    float s[16][4];
#pragma unroll
    for (int tt = 0; tt < 16; ++tt) {
        float4 sv = ((const float4*)SEL)[b * L_DIM + t0 + tt];
        s[tt][0] = sv.x; s[tt][1] = sv.y; s[tt][2] = sv.z; s[tt][3] = sv.w;
    }
    float acc[16] = {};
    const float4* M4 = (const float4*)M;
    for (int i = 0; i < H_DIM; ++i) {
        float4 m = M4[i * H_DIM + j];
#pragma unroll
        for (int tt = 0; tt < 16; ++tt) {
            float a = fmaf(m.x, s[tt][0], fmaf(m.y, s[tt][1],
                      fmaf(m.z, s[tt][2], m.w * s[tt][3])));
            a = fabsf(a);
            acc[tt] += fast_exp2(1.2f * fast_log2(a));  // |a|^1.2
        }
    }
#pragma unroll
    for (int tt = 0; tt < 16; ++tt) {
        rN[(size_t)(b * L_DIM + t0 + tt) * H_DIM + j] =
            fast_exp2(-0.8333333333f * fast_log2(acc[tt]));
    }
}

// ---------------- sequential scan ----------------
// 128 wgs: b = wg&15, slice = wg>>4 (8 slices/batch; all slices of a batch
// land on XCD b%8 under round-robin dispatch -> perf heuristic only).
// Per-batch counter on its OWN 128B line (cnt[b*CNT_STRIDE]) so the LLC
// atomic unit serializes only 8 adds + 8 polls per step, not 16 batches'.
__global__ __launch_bounds__(256, 1) void k_scan(const float* __restrict__ M,
                                                 const float* __restrict__ SEL,
                                                 const float* __restrict__ rN,
                                                 float* __restrict__ out,
                                                 float* hb, unsigned int* cnt) {
    const int wg = blockIdx.x;
    const int b = wg & 15;
    const int slice = wg >> 4;
    const int tid = threadIdx.x;
    const int q = tid >> 6;
    const int ti = tid & 63;
    const int r = ti & 31;
    const int js = ti >> 5;
    const int ig = slice * RPW + r;
    const int jbase = q * 64 + js * 32;

    float m[128];
    {
        const float4* M4 = (const float4*)M;
#pragma unroll
        for (int jj = 0; jj < 32; ++jj) {
            float4 v = M4[ig * H_DIM + jbase + jj];
            m[jj * 4 + 0] = v.x; m[jj * 4 + 1] = v.y;
            m[jj * 4 + 2] = v.z; m[jj * 4 + 3] = v.w;
        }
    }

    __shared__ float g_lds[256];
    __shared__ float part_lds[256];
    unsigned int* cb = cnt + b * CNT_STRIDE;

#pragma unroll 1
    for (int t = 0; t < L_DIM; ++t) {
        // loads independent of other wgs: issue before the poll
        float rn = rN[(size_t)(b * L_DIM + t) * H_DIM + tid];
        float4 s4 = ((const float4*)SEL)[b * L_DIM + t];
        float uval = 0.0f;
        if (tid < RPW) uval = out[(size_t)(b * L_DIM + t) * H_DIM + slice * RPW + tid];

        if (t > 0) {
            if (tid < 64) {  // only wave 0 polls
                unsigned int target = (unsigned int)(SLICES * t);
                while (__hip_atomic_load(cb, __ATOMIC_RELAXED, __HIP_MEMORY_SCOPE_AGENT) < target)
                    __builtin_amdgcn_s_sleep(1);
                __hip_atomic_load(cb, __ATOMIC_ACQUIRE, __HIP_MEMORY_SCOPE_AGENT);
            }
            __syncthreads();
        }
        float h = __hip_atomic_load(hb + (size_t)(t & 1) * (16 * 256) + b * 256 + tid,
                                    __ATOMIC_RELAXED, __HIP_MEMORY_SCOPE_AGENT);
        g_lds[tid] = h * rn;
        __syncthreads();

        float acc0 = 0, acc1 = 0, acc2 = 0, acc3 = 0;
        const float4* g4 = (const float4*)(g_lds + jbase);
#pragma unroll
        for (int jj4 = 0; jj4 < 8; ++jj4) {
            float4 gv = g4[jj4];
            acc0 = fmaf(m[(jj4 * 4 + 0) * 4 + 0], gv.x, acc0);
            acc1 = fmaf(m[(jj4 * 4 + 0) * 4 + 1], gv.x, acc1);
            acc2 = fmaf(m[(jj4 * 4 + 0) * 4 + 2], gv.x, acc2);
            acc3 = fmaf(m[(jj4 * 4 + 0) * 4 + 3], gv.x, acc3);
            acc0 = fmaf(m[(jj4 * 4 + 1) * 4 + 0], gv.y, acc0);
            acc1 = fmaf(m[(jj4 * 4 + 1) * 4 + 1], gv.y, acc1);
            acc2 = fmaf(m[(jj4 * 4 + 1) * 4 + 2], gv.y, acc2);
            acc3 = fmaf(m[(jj4 * 4 + 1) * 4 + 3], gv.y, acc3);
            acc0 = fmaf(m[(jj4 * 4 + 2) * 4 + 0], gv.z, acc0);
            acc1 = fmaf(m[(jj4 * 4 + 2) * 4 + 1], gv.z, acc1);
            acc2 = fmaf(m[(jj4 * 4 + 2) * 4 + 2], gv.z, acc2);
            acc3 = fmaf(m[(jj4 * 4 + 2) * 4 + 3], gv.z, acc3);
            acc0 = fmaf(m[(jj4 * 4 + 3) * 4 + 0], gv.w, acc0);
            acc1 = fmaf(m[(jj4 * 4 + 3) * 4 + 1], gv.w, acc1);
            acc2 = fmaf(m[(jj4 * 4 + 3) * 4 + 2], gv.w, acc2);
            acc3 = fmaf(m[(jj4 * 4 + 3) * 4 + 3], gv.w, acc3);
        }
        float part = fmaf(acc0, s4.x, fmaf(acc1, s4.y, fmaf(acc2, s4.z, acc3 * s4.w)));
        part_lds[tid] = part;
        __syncthreads();

        if (tid < RPW) {
            float hn = uval;
#pragma unroll
            for (int p = 0; p < 8; ++p) hn += part_lds[tid + 32 * p];
            out[(size_t)(b * L_DIM + t) * H_DIM + slice * RPW + tid] = hn;
            __hip_atomic_store(hb + (size_t)((t + 1) & 1) * (16 * 256) + b * 256 + slice * RPW + tid,
                               hn, __ATOMIC_RELAXED, __HIP_MEMORY_SCOPE_AGENT);
        }
        __syncthreads();
        if (tid == 0)
            __hip_atomic_fetch_add(cb, 1u, __ATOMIC_RELEASE, __HIP_MEMORY_SCOPE_AGENT);
    }
}

extern "C" void kernel_launch(void* const* d_in, const int* in_sizes, int n_in,
                              void* d_out, int out_size, void* d_ws, size_t ws_size,
                              hipStream_t stream) {
    const float* x    = (const float*)d_in[0];  // (16,1024,512)
    const float* Wsel = (const float*)d_in[1];  // (4,512)
    const float* bsel = (const float*)d_in[2];  // (4,)
    const float* W_B  = (const float*)d_in[3];  // (256,512)
    const float* M    = (const float*)d_in[4];  // (256,256,4)
    float* out = (float*)d_out;                 // (16,1024,256)

    char* ws = (char*)d_ws;
    unsigned int* cnt = (unsigned int*)(ws + OFF_CNT);
    float* hb  = (float*)(ws + OFF_HB);
    float* SEL = (float*)(ws + OFF_SEL);
    float* rN  = (float*)(ws + OFF_RN);

    k_init<<<1, 512, 0, stream>>>(cnt, hb);
    k_sel<<<(B_DIM * L_DIM) / 4, 256, 0, stream>>>(x, Wsel, bsel, SEL);
    k_u<<<dim3(H_DIM / GBN, (B_DIM * L_DIM) / GBM), 256, 0, stream>>>(x, W_B, out);
    k_norm<<<(B_DIM * L_DIM) / 16, 256, 0, stream>>>(M, SEL, rN);
    k_scan<<<B_DIM * SLICES, 256, 0, stream>>>(M, SEL, rN, out, hb, cnt);
}

// Round 5
// 1367.604 us; speedup vs baseline: 6.5735x; 2.6465x over previous
//
#include <hip/hip_runtime.h>

#define B_DIM 16
#define L_DIM 1024
#define D_DIM 512
#define H_DIM 256
#define K_DIM 4

#define SLICES 8        // wgs per batch
#define RPW 32          // rows per wg (H_DIM / SLICES)

// ---------------- workspace layout (bytes) ----------------
#define OFF_HB  0                      // u64 hb[2][16][256] (tag<<32 | f32 bits), 64KB
#define OFF_SEL 65536                  // float SEL[16384*4]
#define OFF_RN  327680                 // float rN[16384*256]

__device__ __forceinline__ float fast_log2(float x) { return __builtin_amdgcn_logf(x); }
__device__ __forceinline__ float fast_exp2(float x) { return __builtin_amdgcn_exp2f(x); }

// ---------------- init: zero tagged h state (tag=0, h=0) ----------------
__global__ void k_init(unsigned long long* hb) {
    int tid = blockIdx.x * blockDim.x + threadIdx.x;
    for (int i = tid; i < 2 * 16 * 256; i += 512) hb[i] = 0ull;
}

// ---------------- selector GEMM + softmax ----------------
__global__ __launch_bounds__(256) void k_sel(const float* __restrict__ x,
                                             const float* __restrict__ Wsel,
                                             const float* __restrict__ bsel,
                                             float* __restrict__ SEL) {
    int row  = blockIdx.x * 4 + (threadIdx.x >> 6);
    int lane = threadIdx.x & 63;
    const float4* x4 = (const float4*)(x + (size_t)row * D_DIM);
    const float4* w4 = (const float4*)Wsel;
    float4 xa = x4[lane * 2], xb = x4[lane * 2 + 1];
    float acc[4];
#pragma unroll
    for (int k = 0; k < 4; ++k) {
        float4 wa = w4[k * (D_DIM / 4) + lane * 2];
        float4 wb = w4[k * (D_DIM / 4) + lane * 2 + 1];
        acc[k] = xa.x * wa.x + xa.y * wa.y + xa.z * wa.z + xa.w * wa.w +
                 xb.x * wb.x + xb.y * wb.y + xb.z * wb.z + xb.w * wb.w;
    }
#pragma unroll
    for (int off = 1; off < 64; off <<= 1) {
#pragma unroll
        for (int k = 0; k < 4; ++k) acc[k] += __shfl_xor(acc[k], off, 64);
    }
    if (lane == 0) {
        float z[4], mx = -1e30f;
#pragma unroll
        for (int k = 0; k < 4; ++k) { z[k] = acc[k] + bsel[k]; mx = fmaxf(mx, z[k]); }
        float e[4], s = 0.0f;
#pragma unroll
        for (int k = 0; k < 4; ++k) { e[k] = fast_exp2((z[k] - mx) * 1.4426950408889634f); s += e[k]; }
        float inv = 1.0f / s;
        float4 o = { e[0] * inv, e[1] * inv, e[2] * inv, e[3] * inv };
        ((float4*)SEL)[row] = o;
    }
}

// ---------------- U = X @ W_B^T (f32 tiled GEMM), written into d_out ----------------
#define GBM 64
#define GBN 64
#define GBK 32
__global__ __launch_bounds__(256) void k_u(const float* __restrict__ X,
                                           const float* __restrict__ W,
                                           float* __restrict__ U) {
    __shared__ float Xs[GBK][GBM + 1];
    __shared__ float Ws[GBK][GBN + 1];
    int tid = threadIdx.x;
    int rb = blockIdx.y * GBM;
    int cb = blockIdx.x * GBN;
    int tr = tid >> 4, tc = tid & 15;
    int lrow = tid >> 2;
    int lcol = (tid & 3) * 8;
    float acc[4][4] = {};
    for (int kt = 0; kt < D_DIM; kt += GBK) {
        float4 xa = *(const float4*)(X + (size_t)(rb + lrow) * D_DIM + kt + lcol);
        float4 xb = *(const float4*)(X + (size_t)(rb + lrow) * D_DIM + kt + lcol + 4);
        float4 wa = *(const float4*)(W + (size_t)(cb + lrow) * D_DIM + kt + lcol);
        float4 wb = *(const float4*)(W + (size_t)(cb + lrow) * D_DIM + kt + lcol + 4);
        __syncthreads();
        Xs[lcol + 0][lrow] = xa.x; Xs[lcol + 1][lrow] = xa.y;
        Xs[lcol + 2][lrow] = xa.z; Xs[lcol + 3][lrow] = xa.w;
        Xs[lcol + 4][lrow] = xb.x; Xs[lcol + 5][lrow] = xb.y;
        Xs[lcol + 6][lrow] = xb.z; Xs[lcol + 7][lrow] = xb.w;
        Ws[lcol + 0][lrow] = wa.x; Ws[lcol + 1][lrow] = wa.y;
        Ws[lcol + 2][lrow] = wa.z; Ws[lcol + 3][lrow] = wa.w;
        Ws[lcol + 4][lrow] = wb.x; Ws[lcol + 5][lrow] = wb.y;
        Ws[lcol + 6][lrow] = wb.z; Ws[lcol + 7][lrow] = wb.w;
        __syncthreads();
#pragma unroll
        for (int kk = 0; kk < GBK; ++kk) {
            float a0 = Xs[kk][tr * 4 + 0], a1 = Xs[kk][tr * 4 + 1];
            float a2 = Xs[kk][tr * 4 + 2], a3 = Xs[kk][tr * 4 + 3];
            float b0 = Ws[kk][tc * 4 + 0], b1 = Ws[kk][tc * 4 + 1];
            float b2 = Ws[kk][tc * 4 + 2], b3 = Ws[kk][tc * 4 + 3];
            acc[0][0] = fmaf(a0, b0, acc[0][0]); acc[0][1] = fmaf(a0, b1, acc[0][1]);
            acc[0][2] = fmaf(a0, b2, acc[0][2]); acc[0][3] = fmaf(a0, b3, acc[0][3]);
            acc[1][0] = fmaf(a1, b0, acc[1][0]); acc[1][1] = fmaf(a1, b1, acc[1][1]);
            acc[1][2] = fmaf(a1, b2, acc[1][2]); acc[1][3] = fmaf(a1, b3, acc[1][3]);
            acc[2][0] = fmaf(a2, b0, acc[2][0]); acc[2][1] = fmaf(a2, b1, acc[2][1]);
            acc[2][2] = fmaf(a2, b2, acc[2][2]); acc[2][3] = fmaf(a2, b3, acc[2][3]);
            acc[3][0] = fmaf(a3, b0, acc[3][0]); acc[3][1] = fmaf(a3, b1, acc[3][1]);
            acc[3][2] = fmaf(a3, b2, acc[3][2]); acc[3][3] = fmaf(a3, b3, acc[3][3]);
        }
        __syncthreads();
    }
#pragma unroll
    for (int mi = 0; mi < 4; ++mi) {
        float4 v = { acc[mi][0], acc[mi][1], acc[mi][2], acc[mi][3] };
        *(float4*)(U + (size_t)(rb + tr * 4 + mi) * H_DIM + cb + tc * 4) = v;
    }
}

// ---------------- reciprocal Lp column norms ----------------
__global__ __launch_bounds__(256) void k_norm(const float* __restrict__ M,
                                              const float* __restrict__ SEL,
                                              float* __restrict__ rN) {
    int wg = blockIdx.x;
    int b = wg >> 6;
    int t0 = (wg & 63) << 4;
    int j = threadIdx.x;
    float s[16][4];
#pragma unroll
    for (int tt = 0; tt < 16; ++tt) {
        float4 sv = ((const float4*)SEL)[b * L_DIM + t0 + tt];
        s[tt][0] = sv.x; s[tt][1] = sv.y; s[tt][2] = sv.z; s[tt][3] = sv.w;
    }
    float acc[16] = {};
    const float4* M4 = (const float4*)M;
    for (int i = 0; i < H_DIM; ++i) {
        float4 m = M4[i * H_DIM + j];
#pragma unroll
        for (int tt = 0; tt < 16; ++tt) {
            float a = fmaf(m.x, s[tt][0], fmaf(m.y, s[tt][1],
                      fmaf(m.z, s[tt][2], m.w * s[tt][3])));
            a = fabsf(a);
            acc[tt] += fast_exp2(1.2f * fast_log2(a));  // |a|^1.2
        }
    }
#pragma unroll
    for (int tt = 0; tt < 16; ++tt) {
        rN[(size_t)(b * L_DIM + t0 + tt) * H_DIM + j] =
            fast_exp2(-0.8333333333f * fast_log2(acc[tt]));
    }
}

// ---------------- sequential scan (tagged-word sync) ----------------
// 128 wgs: b = wg&15, slice = wg>>4. Each h element travels as a 64-bit
// word (tag=step)<<32 | f32 bits. A reader's poll IS the data load: writer
// 1 relaxed store, reader 1 polled relaxed load -> ~2 LLC round trips/step.
// Double-buffered by step parity; exact-tag match (max skew = 1 step, since
// a writer 2 steps ahead would first stall polling the slow wg's words).
__global__ __launch_bounds__(256, 1) void k_scan(const float* __restrict__ M,
                                                 const float* __restrict__ SEL,
                                                 const float* __restrict__ rN,
                                                 float* __restrict__ out,
                                                 unsigned long long* hb) {
    const int wg = blockIdx.x;
    const int b = wg & 15;
    const int slice = wg >> 4;
    const int tid = threadIdx.x;
    const int q = tid >> 6;
    const int ti = tid & 63;
    const int r = ti & 31;
    const int js = ti >> 5;
    const int ig = slice * RPW + r;
    const int jbase = q * 64 + js * 32;

    float m[128];
    {
        const float4* M4 = (const float4*)M;
#pragma unroll
        for (int jj = 0; jj < 32; ++jj) {
            float4 v = M4[ig * H_DIM + jbase + jj];
            m[jj * 4 + 0] = v.x; m[jj * 4 + 1] = v.y;
            m[jj * 4 + 2] = v.z; m[jj * 4 + 3] = v.w;
        }
    }

    __shared__ float g_lds[256];
    __shared__ float part_lds[256];

#pragma unroll 1
    for (int t = 0; t < L_DIM; ++t) {
        // independent loads issued before the poll (latency hidden under it)
        float rn = rN[(size_t)(b * L_DIM + t) * H_DIM + tid];
        float4 s4 = ((const float4*)SEL)[b * L_DIM + t];
        float uval = 0.0f;
        if (tid < RPW) uval = out[(size_t)(b * L_DIM + t) * H_DIM + slice * RPW + tid];

        // poll own tagged word for step t
        unsigned long long* src = hb + (size_t)(t & 1) * (16 * 256) + b * 256 + tid;
        unsigned long long w;
        while (((w = __hip_atomic_load(src, __ATOMIC_RELAXED, __HIP_MEMORY_SCOPE_AGENT)) >> 32)
               != (unsigned int)t)
            __builtin_amdgcn_s_sleep(1);
        float h = __uint_as_float((unsigned int)w);
        g_lds[tid] = h * rn;
        __syncthreads();

        float acc0 = 0, acc1 = 0, acc2 = 0, acc3 = 0;
        const float4* g4 = (const float4*)(g_lds + jbase);
#pragma unroll
        for (int jj4 = 0; jj4 < 8; ++jj4) {
            float4 gv = g4[jj4];
            acc0 = fmaf(m[(jj4 * 4 + 0) * 4 + 0], gv.x, acc0);
            acc1 = fmaf(m[(jj4 * 4 + 0) * 4 + 1], gv.x, acc1);
            acc2 = fmaf(m[(jj4 * 4 + 0) * 4 + 2], gv.x, acc2);
            acc3 = fmaf(m[(jj4 * 4 + 0) * 4 + 3], gv.x, acc3);
            acc0 = fmaf(m[(jj4 * 4 + 1) * 4 + 0], gv.y, acc0);
            acc1 = fmaf(m[(jj4 * 4 + 1) * 4 + 1], gv.y, acc1);
            acc2 = fmaf(m[(jj4 * 4 + 1) * 4 + 2], gv.y, acc2);
            acc3 = fmaf(m[(jj4 * 4 + 1) * 4 + 3], gv.y, acc3);
            acc0 = fmaf(m[(jj4 * 4 + 2) * 4 + 0], gv.z, acc0);
            acc1 = fmaf(m[(jj4 * 4 + 2) * 4 + 1], gv.z, acc1);
            acc2 = fmaf(m[(jj4 * 4 + 2) * 4 + 2], gv.z, acc2);
            acc3 = fmaf(m[(jj4 * 4 + 2) * 4 + 3], gv.z, acc3);
            acc0 = fmaf(m[(jj4 * 4 + 3) * 4 + 0], gv.w, acc0);
            acc1 = fmaf(m[(jj4 * 4 + 3) * 4 + 1], gv.w, acc1);
            acc2 = fmaf(m[(jj4 * 4 + 3) * 4 + 2], gv.w, acc2);
            acc3 = fmaf(m[(jj4 * 4 + 3) * 4 + 3], gv.w, acc3);
        }
        float part = fmaf(acc0, s4.x, fmaf(acc1, s4.y, fmaf(acc2, s4.z, acc3 * s4.w)));
        part_lds[tid] = part;
        __syncthreads();

        if (tid < RPW) {
            float hn = uval;
#pragma unroll
            for (int p = 0; p < 8; ++p) hn += part_lds[tid + 32 * p];
            out[(size_t)(b * L_DIM + t) * H_DIM + slice * RPW + tid] = hn;
            unsigned long long pw = ((unsigned long long)(unsigned int)(t + 1) << 32) |
                                    (unsigned long long)__float_as_uint(hn);
            __hip_atomic_store(hb + (size_t)((t + 1) & 1) * (16 * 256) + b * 256 + slice * RPW + tid,
                               pw, __ATOMIC_RELAXED, __HIP_MEMORY_SCOPE_AGENT);
        }
        // no trailing barrier: part_lds is next written only after the next
        // __syncthreads; g_lds readers all passed the part_lds barrier.
    }
}

extern "C" void kernel_launch(void* const* d_in, const int* in_sizes, int n_in,
                              void* d_out, int out_size, void* d_ws, size_t ws_size,
                              hipStream_t stream) {
    const float* x    = (const float*)d_in[0];  // (16,1024,512)
    const float* Wsel = (const float*)d_in[1];  // (4,512)
    const float* bsel = (const float*)d_in[2];  // (4,)
    const float* W_B  = (const float*)d_in[3];  // (256,512)
    const float* M    = (const float*)d_in[4];  // (256,256,4)
    float* out = (float*)d_out;                 // (16,1024,256)

    char* ws = (char*)d_ws;
    unsigned long long* hb = (unsigned long long*)(ws + OFF_HB);
    float* SEL = (float*)(ws + OFF_SEL);
    float* rN  = (float*)(ws + OFF_RN);

    k_init<<<1, 512, 0, stream>>>(hb);
    k_sel<<<(B_DIM * L_DIM) / 4, 256, 0, stream>>>(x, Wsel, bsel, SEL);
    k_u<<<dim3(H_DIM / GBN, (B_DIM * L_DIM) / GBM), 256, 0, stream>>>(x, W_B, out);
    k_norm<<<(B_DIM * L_DIM) / 16, 256, 0, stream>>>(M, SEL, rN);
    k_scan<<<B_DIM * SLICES, 256, 0, stream>>>(M, SEL, rN, out, hb);
}